// Round 1
// baseline (534.282 us; speedup 1.0000x reference)
//
#include <hip/hip_runtime.h>

// Correlation cost volume, fp32.
//   out[b,i,h,x] = (1/256) * sum_c left[b,c,h,x] * right[b,c,h,x-i]   for x>=i, else 0
// b=4 c=256 h=180 w=320, 64 disparities.
//
// Strategy: one block per (b,h) row (720 blocks, 320 threads = 5 waves).
// K-chunked LDS staging (16 channels/chunk) of the full 320-wide left row and
// the right row with a 64-float zero halo (for x-i < 0). Each thread owns an
// 8(disp) x 8(x) fp32 register accumulator tile: per channel it reads a
// 16-float right window (4x ds_read_b128) + 8-float left segment (2x b128)
// and does 64 v_fmac_f32. LDS granules are swizzled (PG = G + (G>>3)) to break
// the even-granule 4-deep bank-group collision pattern of the window reads.

#define Bb 4
#define Cc 256
#define Hh 180
#define Ww 320
#define MAXD 64
#define KC 16          // channels staged per chunk
#define NT 320         // threads per block (5 waves)
#define RSTRIDE 432    // right row: 96 logical granules -> 107 phys -> pad to 108*4 words
#define LSTRIDE 360    // left row: 80 logical granules -> 89 phys -> pad to 90*4 words

// additive granule swizzle: logical word -> physical word (16B granule granularity)
__device__ __forceinline__ int swz(int w) {
    int G = w >> 2;
    G = G + (G >> 3);
    return (G << 2) | (w & 3);
}

__global__ __launch_bounds__(NT, 4)
void _AA_CostVolume_63668595196248_kernel(const float* __restrict__ left,
                                          const float* __restrict__ right,
                                          float* __restrict__ out) {
    __shared__ float lds_r[KC][RSTRIDE];
    __shared__ float lds_l[KC][LSTRIDE];

    const int tid = threadIdx.x;
    const int bi  = blockIdx.x;
    const int b   = bi / Hh;
    const int h   = bi % Hh;

    const int threadi = tid & 7;    // 8 disparity groups (i0 = 8*threadi)
    const int threadx = tid >> 3;   // 40 x groups (tx = 8*threadx)
    const int tx = threadx << 3;
    const int i0 = threadi << 3;

    // zero the halo (logical words [0,64) of each right row == right index < 0)
    if (tid < KC * 16) {
        const int row = tid >> 4;
        const int g4  = tid & 15;
        *(float4*)&lds_r[row][swz(g4 << 2)] = make_float4(0.f, 0.f, 0.f, 0.f);
    }

    // hoisted swizzled read offsets (row-relative); window logical base p = 56 + tx - i0
    int roff[4], loff[2];
    {
        const int p = 56 + tx - i0;   // in [0, 368], multiple of 8
#pragma unroll
        for (int ii = 0; ii < 4; ++ii) roff[ii] = swz(p + (ii << 2));
#pragma unroll
        for (int ii = 0; ii < 2; ++ii) loff[ii] = swz(tx + (ii << 2));
    }

    // staging constants: 80 threads x 80 float4 cover one 320-float row
    const int tdiv = tid / 80;        // 0..3 : row subgroup
    const int tmod = tid % 80;        // float4 column within row
    const int xcol = tmod << 2;
    const int rdst = swz(64 + xcol);  // right rows live at logical words [64, 384)
    const int ldst = swz(xcol);
    const int gbase = b * (Cc * Hh * Ww) + h * Ww + xcol;

    float acc[8][8];
#pragma unroll
    for (int di = 0; di < 8; ++di)
#pragma unroll
        for (int dx = 0; dx < 8; ++dx) acc[di][dx] = 0.f;

    for (int k0 = 0; k0 < Cc; k0 += KC) {
        __syncthreads();   // previous chunk's compute done (also orders halo zeroing)
#pragma unroll
        for (int u = 0; u < 4; ++u) {
            const int row = (u << 2) + tdiv;
            const int src = gbase + (k0 + row) * (Hh * Ww);
            const float4 rv = *(const float4*)(right + src);
            const float4 lv = *(const float4*)(left + src);
            *(float4*)&lds_r[row][rdst] = rv;
            *(float4*)&lds_l[row][ldst] = lv;
        }
        __syncthreads();

#pragma unroll 4
        for (int s = 0; s < KC; ++s) {
            const float* __restrict__ rr = lds_r[s];
            const float* __restrict__ lr = lds_l[s];
            float r[16], l[8];
#pragma unroll
            for (int ii = 0; ii < 4; ++ii)
                *(float4*)&r[ii << 2] = *(const float4*)&rr[roff[ii]];
#pragma unroll
            for (int ii = 0; ii < 2; ++ii)
                *(float4*)&l[ii << 2] = *(const float4*)&lr[loff[ii]];
            // r[j] = right[k][tx - i0 - 8 + j]; need right[(tx+dx)-(i0+di)] -> j = 8+dx-di
#pragma unroll
            for (int di = 0; di < 8; ++di)
#pragma unroll
                for (int dx = 0; dx < 8; ++dx)
                    acc[di][dx] += l[dx] * r[8 + dx - di];
        }
    }

    // epilogue: scale by 1/256, zero invalid (x < i), coalesced float4 stores
    const float scale = 1.0f / 256.0f;
#pragma unroll
    for (int di = 0; di < 8; ++di) {
        const int i = i0 + di;
        float v[8];
#pragma unroll
        for (int dx = 0; dx < 8; ++dx)
            v[dx] = (tx + dx >= i) ? acc[di][dx] * scale : 0.f;
        const int o = ((b * MAXD + i) * Hh + h) * Ww + tx;
        *(float4*)(out + o)     = make_float4(v[0], v[1], v[2], v[3]);
        *(float4*)(out + o + 4) = make_float4(v[4], v[5], v[6], v[7]);
    }
}

extern "C" void kernel_launch(void* const* d_in, const int* in_sizes, int n_in,
                              void* d_out, int out_size, void* d_ws, size_t ws_size,
                              hipStream_t stream) {
    const float* left  = (const float*)d_in[0];
    const float* right = (const float*)d_in[1];
    float* out = (float*)d_out;
    dim3 grid(Bb * Hh);
    dim3 block(NT);
    _AA_CostVolume_63668595196248_kernel<<<grid, block, 0, stream>>>(left, right, out);
}

// Round 2
// 503.128 us; speedup vs baseline: 1.0619x; 1.0619x over previous
//
#include <hip/hip_runtime.h>

// Correlation cost volume as a banded bf16 MFMA GEMM.
//   out[b,i,h,x] = (1/256) * sum_c L[b,c,h,x] * R[b,c,h,x-i],  x>=i, else 0.
// Per (b,h) row: C[x,y] = sum_c L[c,x] R[c,y] on the band y in [x-63, x], y>=0.
// 16x16 tiles via mfma_f32_16x16x32_bf16; x-tile t needs y-tiles max(0,t-4)..t.
//
// Block = one (b,h) row, 320 threads = 5 waves; wave w owns x-tiles 4w..4w+3
// (acc: 4 x-tiles x up-to-5 diagonals x f32x4 = 80 regs). K is chunked 32
// channels at a time; L,R staged in LDS transposed to [x][c] bf16 (RNE), row
// stride 20 dwords (16B-aligned rows for ds_read_b128; both the b32 staging
// writes and the b128 fragment reads are 2-way bank-balanced = free).
// Invalid region (x < i) is zero-filled up front.

typedef short bf16x8 __attribute__((ext_vector_type(8)));
typedef float f32x4 __attribute__((ext_vector_type(4)));

#define Bb 4
#define Cc 256
#define Hh 180
#define Ww 320
#define MAXD 64
#define KC 32            // channels per K-chunk
#define NCHUNK (Cc / KC) // 8
#define RSTR 20          // dwords per x-row in LDS (16 data + 4 pad)
#define HW (Hh * Ww)

// pack two floats to packed bf16 (lo=a, hi=b), round-to-nearest-even
__device__ __forceinline__ unsigned int bf16rne2(float a, float b) {
    unsigned int ua = __float_as_uint(a);
    unsigned int ub = __float_as_uint(b);
    ua = (ua + 0x7FFFu + ((ua >> 16) & 1u)) >> 16;
    ub = (ub + 0x7FFFu + ((ub >> 16) & 1u)) & 0xFFFF0000u;
    return ua | ub;
}

__global__ __launch_bounds__(320, 3)
void _AA_CostVolume_63668595196248_kernel(const float* __restrict__ L,
                                          const float* __restrict__ R,
                                          float* __restrict__ out) {
    __shared__ unsigned int sL[Ww * RSTR];
    __shared__ unsigned int sR[Ww * RSTR];

    const int tid = threadIdx.x;
    const int bi  = blockIdx.x;
    const int b   = bi / Hh;
    const int h   = bi % Hh;

    // zero-fill invalid outputs (x < i): 2016 dwords per (b,h)
    {
        const int ob = (b * MAXD * Hh + h) * Ww;
        for (int z = tid; z < MAXD * MAXD; z += 320) {
            const int i = z >> 6;
            const int x = z & 63;
            if (x < i) out[ob + i * HW + x] = 0.0f;
        }
    }

    const int lane = tid & 63;
    const int w    = tid >> 6;      // wave id 0..4
    const int q    = lane >> 4;     // quad 0..3
    const int n    = lane & 15;     // fragment row/col index

    // staging decomposition: cp = channel-pair (dword col), tq -> x quad
    const int cp = tid & 15;
    const int tq = tid >> 4;        // 0..19
    const int inbase = (b * Cc + 2 * cp) * HW + h * Ww;

    const int frag_off = n * RSTR + 4 * q;  // dword offset within a 16-row tile

    f32x4 acc[4][5];
#pragma unroll
    for (int xt = 0; xt < 4; ++xt)
#pragma unroll
        for (int du = 0; du < 5; ++du) {
            f32x4 z = {0.f, 0.f, 0.f, 0.f};
            acc[xt][du] = z;
        }

    for (int kc = 0; kc < NCHUNK; ++kc) {
        __syncthreads();   // previous chunk's fragment reads done
        const float* Lp = L + inbase + kc * KC * HW;
        const float* Rp = R + inbase + kc * KC * HW;
#pragma unroll
        for (int s = 0; s < 4; ++s) {
            const int xq = tq + 20 * s;
            const float4 l0 = *(const float4*)(Lp + 4 * xq);
            const float4 l1 = *(const float4*)(Lp + HW + 4 * xq);
            const float4 r0 = *(const float4*)(Rp + 4 * xq);
            const float4 r1 = *(const float4*)(Rp + HW + 4 * xq);
            const float* l0f = (const float*)&l0;
            const float* l1f = (const float*)&l1;
            const float* r0f = (const float*)&r0;
            const float* r1f = (const float*)&r1;
#pragma unroll
            for (int j = 0; j < 4; ++j) {
                sL[(4 * xq + j) * RSTR + cp] = bf16rne2(l0f[j], l1f[j]);
                sR[(4 * xq + j) * RSTR + cp] = bf16rne2(r0f[j], r1f[j]);
            }
        }
        __syncthreads();

        // A fragments for this wave's 4 x-tiles
        bf16x8 af[4];
#pragma unroll
        for (int xt = 0; xt < 4; ++xt)
            af[xt] = *(const bf16x8*)&sL[(16 * (4 * w + xt) + n) * RSTR + 4 * q];

        // B fragments over the y-tile window [4w-4, 4w+3]
#pragma unroll
        for (int uu = 0; uu < 8; ++uu) {
            const int u = 4 * w + uu - 4;
            if (u >= 0) {   // wave-uniform
                const bf16x8 bfr = *(const bf16x8*)&sR[u * (16 * RSTR) + frag_off];
#pragma unroll
                for (int xt = 0; xt < 4; ++xt) {
                    const int du = xt - (uu - 4);   // compile-time
                    if (du >= 0 && du <= 4)
                        acc[xt][du] = __builtin_amdgcn_mfma_f32_16x16x32_bf16(
                            af[xt], bfr, acc[xt][du], 0, 0, 0);
                }
            }
        }
    }

    // epilogue: lane holds D[m = 4q+r][n] of tile (t, u=t-du); i = x - y
    const float sc = 1.0f / 256.0f;
#pragma unroll
    for (int xt = 0; xt < 4; ++xt) {
        const int t  = 4 * w + xt;
        const int x0 = 16 * t + 4 * q;
#pragma unroll
        for (int du = 0; du < 5; ++du) {
            if (t - du >= 0) {   // u >= 0, wave-uniform
                const int ib = 16 * du + 4 * q - n;
#pragma unroll
                for (int r = 0; r < 4; ++r) {
                    const int i = ib + r;
                    if (i >= 0 && i < MAXD)
                        out[((b * MAXD + i) * Hh + h) * Ww + x0 + r] = acc[xt][du][r] * sc;
                }
            }
        }
    }
}

extern "C" void kernel_launch(void* const* d_in, const int* in_sizes, int n_in,
                              void* d_out, int out_size, void* d_ws, size_t ws_size,
                              hipStream_t stream) {
    const float* left  = (const float*)d_in[0];
    const float* right = (const float*)d_in[1];
    float* out = (float*)d_out;
    dim3 grid(Bb * Hh);
    dim3 block(320);
    _AA_CostVolume_63668595196248_kernel<<<grid, block, 0, stream>>>(left, right, out);
}